// Round 6
// baseline (309.994 us; speedup 1.0000x reference)
//
#include <hip/hip_runtime.h>
#include <hip/hip_bf16.h>

// MHA: B=2 S=2048 DM=1024 H=16 DK=64.  All heavy math in bf16 MFMA, fp32 accum.
#define DM 1024
#define SL 2048
#define NH 16
#define DK 64

typedef __bf16 bf16;
typedef __bf16 bf16x8 __attribute__((ext_vector_type(8)));
typedef __bf16 bf16x4 __attribute__((ext_vector_type(4)));
typedef float f32x4 __attribute__((ext_vector_type(4)));
typedef float f32x16 __attribute__((ext_vector_type(16)));
typedef unsigned u32x4 __attribute__((ext_vector_type(4)));

__device__ __forceinline__ void gll16(const void* g, void* l) {
  __builtin_amdgcn_global_load_lds(
      (const __attribute__((address_space(1))) unsigned int*)g,
      (__attribute__((address_space(3))) unsigned int*)l, 16, 0, 0);
}

__device__ __forceinline__ unsigned pk2(float a, float b) {
  unsigned short lo = __builtin_bit_cast(unsigned short, (bf16)a);
  unsigned short hi = __builtin_bit_cast(unsigned short, (bf16)b);
  return (unsigned)lo | ((unsigned)hi << 16);
}

// ---------------- fused prep: fp32->bf16 for q,k,v  +  W^T bf16 for 4 weights ---
__global__ __launch_bounds__(256) void prep_kernel(
    const float* __restrict__ q, const float* __restrict__ k, const float* __restrict__ v,
    const float* __restrict__ Wq, const float* __restrict__ Wk,
    const float* __restrict__ Wv, const float* __restrict__ Wo,
    bf16* __restrict__ xq, bf16* __restrict__ xk, bf16* __restrict__ xv,
    bf16* __restrict__ TQ, bf16* __restrict__ TK, bf16* __restrict__ TV,
    bf16* __restrict__ TO) {
  __shared__ float t[64][65];
  const int bid = blockIdx.x, tid = threadIdx.x;
  if (bid < 6144) {
    const float* src; bf16* dst;
    if (bid < 2048)      { src = q; dst = xq; }
    else if (bid < 4096) { src = k; dst = xk; }
    else                 { src = v; dst = xv; }
    int i = (bid & 2047) * 2048 + tid * 8;
    f32x4 a = *(const f32x4*)(src + i);
    f32x4 b = *(const f32x4*)(src + i + 4);
    bf16x8 o;
    o[0]=(bf16)a[0]; o[1]=(bf16)a[1]; o[2]=(bf16)a[2]; o[3]=(bf16)a[3];
    o[4]=(bf16)b[0]; o[5]=(bf16)b[1]; o[6]=(bf16)b[2]; o[7]=(bf16)b[3];
    *(bf16x8*)(dst + i) = o;
  } else {
    const int wb = bid - 6144;
    const float* W; bf16* T;
    switch (wb >> 8) {
      case 0:  W = Wq; T = TQ; break;
      case 1:  W = Wk; T = TK; break;
      case 2:  W = Wv; T = TV; break;
      default: W = Wo; T = TO; break;
    }
    const int tile = wb & 255;
    const int tx = tile & 15, ty = tile >> 4;   // n-tile tx, k-tile ty
    const int cr = tid >> 4, cc = tid & 15;
    #pragma unroll
    for (int rr = 0; rr < 4; ++rr) {
      int row = rr*16 + cr;
      f32x4 val = *(const f32x4*)(W + (ty*64 + row)*DM + tx*64 + cc*4);
      t[row][cc*4+0] = val[0]; t[row][cc*4+1] = val[1];
      t[row][cc*4+2] = val[2]; t[row][cc*4+3] = val[3];
    }
    __syncthreads();
    #pragma unroll
    for (int rr = 0; rr < 4; ++rr) {
      int nrow = rr*16 + cr;
      bf16x4 o;
      o[0] = (bf16)t[cc*4+0][nrow]; o[1] = (bf16)t[cc*4+1][nrow];
      o[2] = (bf16)t[cc*4+2][nrow]; o[3] = (bf16)t[cc*4+3][nrow];
      *(bf16x4*)(T + (tx*64 + nrow)*DM + ty*64 + cc*4) = o;
    }
  }
}

// ------------- 64x128 tile GEMM, BK=64, DOUBLE-BUFFERED global_load_lds ---------
// C[m][n] = sum_k A[m][k]*Bt[n][k] (+bias).  4 waves in 2x2 (wave tile 32x64).
// MODE 0: fp32 row-major.  MODE 1: bf16 [bh][s][dk].  MODE 2: bf16 [bh][dk][s].
template<int MODE>
__device__ __forceinline__ void gemm_core(
    const bf16* __restrict__ A, const bf16* __restrict__ Bt, const float* __restrict__ bias,
    bf16* __restrict__ outH, float* __restrict__ outF) {
  const int bid = blockIdx.x;
  const int swz = (bid & 7) * 64 + (bid >> 3);   // XCD-aware bijective (512 blocks)
  const int mt = swz >> 3, nt = swz & 7;
  const int m0 = mt*64, n0 = nt*128;
  __shared__ __attribute__((aligned(16))) bf16 As[2][64*64];
  __shared__ __attribute__((aligned(16))) bf16 Bs[2][128*64];
  const int tid = threadIdx.x, lane = tid & 63, w = tid >> 6;
  const int wm = w >> 1, wn = w & 1;
  f32x4 acc[2][4];
  #pragma unroll
  for (int x = 0; x < 2; ++x)
    #pragma unroll
    for (int y = 0; y < 4; ++y)
      #pragma unroll
      for (int e = 0; e < 4; ++e) acc[x][y][e] = 0.f;

  #define GSTAGE(buf, kt_)                                                 \
    {                                                                      \
      const int k0s = (kt_)*64;                                            \
      _Pragma("unroll")                                                    \
      for (int i = 0; i < 2; ++i) {                                        \
        int idx = (i*4 + w)*64 + lane;                                     \
        int r = idx >> 3;                                                  \
        int s = (idx & 7) ^ (r & 7);                                       \
        gll16(A + (m0 + r)*DM + k0s + s*8, &As[buf][(i*4 + w)*512]);       \
      }                                                                    \
      _Pragma("unroll")                                                    \
      for (int i = 0; i < 4; ++i) {                                        \
        int idx = (i*4 + w)*64 + lane;                                     \
        int r = idx >> 3;                                                  \
        int s = (idx & 7) ^ (r & 7);                                       \
        gll16(Bt + (n0 + r)*DM + k0s + s*8, &Bs[buf][(i*4 + w)*512]);      \
      }                                                                    \
    }

  GSTAGE(0, 0);
  __syncthreads();

  for (int kt = 0; kt < 16; ++kt) {
    const int cur = kt & 1;
    if (kt < 15) GSTAGE(cur ^ 1, kt + 1);     // prefetch flies under compute
    bf16x8 bfr[4][2];
    #pragma unroll
    for (int ni = 0; ni < 4; ++ni) {
      int row = wn*64 + ni*16 + (lane & 15);
      #pragma unroll
      for (int c = 0; c < 2; ++c) {
        int slot = (lane >> 4) + c*4;
        bfr[ni][c] = *(const bf16x8*)&Bs[cur][row*64 + ((slot ^ (row & 7)) << 3)];
      }
    }
    __builtin_amdgcn_s_setprio(1);
    #pragma unroll
    for (int mi = 0; mi < 2; ++mi) {
      int row = wm*32 + mi*16 + (lane & 15);
      bf16x8 a0 = *(const bf16x8*)&As[cur][row*64 + ((((lane >> 4)    ) ^ (row & 7)) << 3)];
      bf16x8 a1 = *(const bf16x8*)&As[cur][row*64 + ((((lane >> 4) + 4) ^ (row & 7)) << 3)];
      #pragma unroll
      for (int ni = 0; ni < 4; ++ni) {
        acc[mi][ni] = __builtin_amdgcn_mfma_f32_16x16x32_bf16(a0, bfr[ni][0], acc[mi][ni], 0, 0, 0);
        acc[mi][ni] = __builtin_amdgcn_mfma_f32_16x16x32_bf16(a1, bfr[ni][1], acc[mi][ni], 0, 0, 0);
      }
    }
    __builtin_amdgcn_s_setprio(0);
    __syncthreads();   // readers done with [cur]; prefetch for [cur^1] drained
  }
  #undef GSTAGE

  #pragma unroll
  for (int ni = 0; ni < 4; ++ni) {
    int n = n0 + wn*64 + ni*16 + (lane & 15);
    float bv = bias[n];
    #pragma unroll
    for (int mi = 0; mi < 2; ++mi) {
      int mb = m0 + wm*32 + mi*16 + ((lane >> 4) << 2);
      if (MODE == 2) {
        int bb = mb >> 11, ss = mb & 2047, hh = n >> 6, dd = n & 63;
        bf16x4 o;
        #pragma unroll
        for (int j = 0; j < 4; ++j) o[j] = (bf16)(acc[mi][ni][j] + bv);
        *(bf16x4*)&outH[(((bb << 4) + hh)*DK + dd)*SL + ss] = o;
      } else {
        #pragma unroll
        for (int j = 0; j < 4; ++j) {
          int m = mb + j;
          float val = acc[mi][ni][j] + bv;
          if (MODE == 1) {
            int bb = m >> 11, ss = m & 2047, hh = n >> 6, dd = n & 63;
            outH[(((bb << 4) + hh)*SL + ss)*DK + dd] = (bf16)val;
          } else {
            outF[m*DM + n] = val;
          }
        }
      }
    }
  }
}

__global__ __launch_bounds__(256, 3) void proj_gemm_kernel(
    const bf16* XQ, const bf16* XK, const bf16* XV,
    const bf16* WTQp, const bf16* WTKp, const bf16* WTVp,
    const float* bq, const float* bk, const float* bv,
    bf16* QHp, bf16* KHp, bf16* VTp) {
  if (blockIdx.y == 0)      gemm_core<1>(XQ, WTQp, bq, QHp, nullptr);
  else if (blockIdx.y == 1) gemm_core<1>(XK, WTKp, bk, KHp, nullptr);
  else                      gemm_core<2>(XV, WTVp, bv, VTp, nullptr);
}

__global__ __launch_bounds__(256, 3) void out_gemm_kernel(
    const bf16* CTXp, const bf16* WTOp, const float* bo, float* out) {
  gemm_core<0>(CTXp, WTOp, bo, nullptr, out);
}

// ---------------- flash attention, swapped-QK^T, 32x32x16 MFMA ----------------
// 4 waves x 32-query strips (QBLK=128), KBLK=64, 2-phase double-buffered staging,
// V pre-transposed (VT[bh][d][s]), in-register P redistribution (static indices),
// defer-max, L2E-folded scores, in-register mask convert, XCD-bh clustering.
__global__ __launch_bounds__(256, 2) void attn_kernel(
    const bf16* __restrict__ QHp, const bf16* __restrict__ KHp,
    const bf16* __restrict__ VTp, const int* __restrict__ msk,
    bf16* __restrict__ CTXp) {
  // bijective XCD swizzle over 512 blocks: xcd owns bh in [4*xcd, 4*xcd+4)
  const int d = blockIdx.x;
  const int xcd = d & 7, rr = d >> 3;
  const int bh = xcd*4 + (rr >> 4);
  const int qt = rr & 15;
  const int b = bh >> 4, h = bh & 15;
  const int q0 = qt * 128;
  const bf16* Qp  = QHp + bh * SL * DK;
  const bf16* Kp  = KHp + bh * SL * DK;
  const bf16* Vtp = VTp + bh * SL * DK;   // [d][s]
  const int* mp = msk + b * SL;
  __shared__ __attribute__((aligned(16))) bf16 Ks[2][64*64];   // [key][d] swizzled
  __shared__ __attribute__((aligned(16))) bf16 Vts[2][64*64];  // [d][key] swizzled
  const int tid = threadIdx.x, lane = tid & 63, w = tid >> 6;
  const int hi = lane >> 5, l5 = lane & 31;
  const float SCL2E = 0.18033688f;   // 0.125 * log2(e)

  // Q fragments (regs whole kernel): B-operand col = q = l5
  bf16x8 qf[4];
  {
    const bf16* qr = Qp + (q0 + w*32 + l5)*DK + hi*8;
    #pragma unroll
    for (int c = 0; c < 4; ++c) qf[c] = *(const bf16x8*)(qr + c*16);
  }
  f32x16 o0, o1;
  #pragma unroll
  for (int e = 0; e < 16; ++e) { o0[e] = 0.f; o1[e] = 0.f; }
  float m_run = -1e30f, l_run = 0.f;   // m_run in log2 units

  #define STAGE(buf, kt_)                                                  \
    {                                                                      \
      const int k0s = (kt_)*64;                                            \
      _Pragma("unroll")                                                    \
      for (int i = 0; i < 2; ++i) {                                        \
        int idx = (i*4 + w)*64 + lane;                                     \
        int r = idx >> 3;                                                  \
        int s = (idx & 7) ^ (r & 7);                                       \
        gll16(Kp + (k0s + r)*DK + s*8, &Ks[buf][(i*4 + w)*512]);           \
      }                                                                    \
      _Pragma("unroll")                                                    \
      for (int i = 0; i < 2; ++i) {                                        \
        int idx = (i*4 + w)*64 + lane;                                     \
        int r = idx >> 3;                                                  \
        int s = (idx & 7) ^ (r & 7);                                       \
        gll16(Vtp + r*SL + k0s + s*8, &Vts[buf][(i*4 + w)*512]);           \
      }                                                                    \
    }

  STAGE(0, 0);
  __syncthreads();

  for (int kt = 0; kt < 32; ++kt) {
    const int cur = kt & 1;
    const int k0 = kt*64;

    // mask -> additive log2-bias, in regs (L2-resident 8KB; before prefetch)
    f32x4 mreg[2][4];
    #pragma unroll
    for (int half = 0; half < 2; ++half)
      #pragma unroll
      for (int qd = 0; qd < 4; ++qd) {
        int4 m4 = *(const int4*)&mp[k0 + half*32 + qd*8 + hi*4];
        mreg[half][qd][0] = m4.x ? 0.f : -1.4426950e9f;
        mreg[half][qd][1] = m4.y ? 0.f : -1.4426950e9f;
        mreg[half][qd][2] = m4.z ? 0.f : -1.4426950e9f;
        mreg[half][qd][3] = m4.w ? 0.f : -1.4426950e9f;
      }

    if (kt < 31) STAGE(cur ^ 1, kt + 1);

    // ST[key][q] = K @ Q^T
    f32x16 s0, s1;
    #pragma unroll
    for (int e = 0; e < 16; ++e) { s0[e] = 0.f; s1[e] = 0.f; }
    __builtin_amdgcn_s_setprio(1);
    #pragma unroll
    for (int c = 0; c < 4; ++c) {
      int sl = 2*c + hi;
      int r0 = l5, r1 = 32 + l5;
      bf16x8 kf0 = *(const bf16x8*)&Ks[cur][r0*64 + ((sl ^ (r0 & 7)) << 3)];
      bf16x8 kf1 = *(const bf16x8*)&Ks[cur][r1*64 + ((sl ^ (r1 & 7)) << 3)];
      s0 = __builtin_amdgcn_mfma_f32_32x32x16_bf16(kf0, qf[c], s0, 0, 0, 0);
      s1 = __builtin_amdgcn_mfma_f32_32x32x16_bf16(kf1, qf[c], s1, 0, 0, 0);
    }
    __builtin_amdgcn_s_setprio(0);

    // scale+mask in log2 units; tree-reduced max
    float pv_[32];
    float mtv0 = -1e30f, mtv1 = -1e30f, mtv2 = -1e30f, mtv3 = -1e30f;
    #pragma unroll
    for (int half = 0; half < 2; ++half) {
      #pragma unroll
      for (int qd = 0; qd < 4; ++qd) {
        f32x4 ma = mreg[half][qd];
        #pragma unroll
        for (int j = 0; j < 4; ++j) {
          float val = (half ? s1[qd*4+j] : s0[qd*4+j]) * SCL2E + ma[j];
          pv_[half*16 + qd*4 + j] = val;
          if (j == 0) mtv0 = fmaxf(mtv0, val);
          else if (j == 1) mtv1 = fmaxf(mtv1, val);
          else if (j == 2) mtv2 = fmaxf(mtv2, val);
          else mtv3 = fmaxf(mtv3, val);
        }
      }
    }
    float mt = fmaxf(fmaxf(mtv0, mtv1), fmaxf(mtv2, mtv3));
    mt = fmaxf(mt, __shfl_xor(mt, 32));
    // defer-max (threshold 8 nats ~ 11.54 log2-units)
    if (!__all(mt - m_run <= 11.5f)) {
      float mnew = fmaxf(m_run, mt);
      float sf = exp2f(m_run - mnew);
      #pragma unroll
      for (int reg = 0; reg < 16; ++reg) {
        int crow = (reg & 3) + ((reg >> 2) << 3) + (hi << 2);
        float s_ = __shfl(sf, crow);
        o0[reg] *= s_; o1[reg] *= s_;
      }
      l_run *= sf;
      m_run = mnew;
    }
    float ls0 = 0.f, ls1 = 0.f, ls2 = 0.f, ls3 = 0.f;
    #pragma unroll
    for (int t = 0; t < 32; ++t) {
      float p = exp2f(pv_[t] - m_run);
      pv_[t] = p;
      if ((t & 3) == 0) ls0 += p;
      else if ((t & 3) == 1) ls1 += p;
      else if ((t & 3) == 2) ls2 += p;
      else ls3 += p;
    }
    float lsum = (ls0 + ls1) + (ls2 + ls3);
    lsum += __shfl_xor(lsum, 32);
    l_run += lsum;

    // PV A-fragment in-register; all pv_ indices static, hi selects registers
    #pragma unroll
    for (int c = 0; c < 4; ++c) {
      const int half_c = c >> 1;
      const int iA = half_c*16 + (((2*c)    ) & 3)*4;
      const int iB = half_c*16 + (((2*c) + 1) & 3)*4;
      unsigned wA0 = pk2(pv_[iA],   pv_[iA+1]);
      unsigned wA1 = pk2(pv_[iA+2], pv_[iA+3]);
      unsigned wB0 = pk2(pv_[iB],   pv_[iB+1]);
      unsigned wB1 = pk2(pv_[iB+2], pv_[iB+3]);
      unsigned ow0 = hi ? wB0 : wA0, ow1 = hi ? wB1 : wA1;
      unsigned xw0 = hi ? wA0 : wB0, xw1 = hi ? wA1 : wB1;
      unsigned yw0 = __shfl_xor(xw0, 32);
      unsigned yw1 = __shfl_xor(xw1, 32);
      u32x4 uu;
      uu[0] = hi ? yw0 : ow0;
      uu[1] = hi ? yw1 : ow1;
      uu[2] = hi ? ow0 : yw0;
      uu[3] = hi ? ow1 : yw1;
      bf16x8 pa = __builtin_bit_cast(bf16x8, uu);
      int sl = 2*c + hi;
      int r0 = l5, r1 = 32 + l5;
      bf16x8 vf0 = *(const bf16x8*)&Vts[cur][r0*64 + ((sl ^ (r0 & 7)) << 3)];
      bf16x8 vf1 = *(const bf16x8*)&Vts[cur][r1*64 + ((sl ^ (r1 & 7)) << 3)];
      __builtin_amdgcn_s_setprio(1);
      o0 = __builtin_amdgcn_mfma_f32_32x32x16_bf16(pa, vf0, o0, 0, 0, 0);
      o1 = __builtin_amdgcn_mfma_f32_32x32x16_bf16(pa, vf1, o1, 0, 0, 0);
      __builtin_amdgcn_s_setprio(0);
    }
    __syncthreads();
  }

  // epilogue
  float inv = 1.f / l_run;
  const int sbase = (b * SL) * DM + h * DK;
  #pragma unroll
  for (int reg = 0; reg < 16; ++reg) {
    int crow = (reg & 3) + ((reg >> 2) << 3) + (hi << 2);
    float iv = __shfl(inv, crow);
    int srow = q0 + w*32 + crow;
    CTXp[sbase + srow*DM + l5]      = (bf16)(o0[reg] * iv);
    CTXp[sbase + srow*DM + 32 + l5] = (bf16)(o1[reg] * iv);
  }
  #undef STAGE
}

extern "C" void kernel_launch(void* const* d_in, const int* in_sizes, int n_in,
                              void* d_out, int out_size, void* d_ws, size_t ws_size,
                              hipStream_t stream) {
  const float* q  = (const float*)d_in[0];
  const float* k  = (const float*)d_in[1];
  const float* v  = (const float*)d_in[2];
  const int*  msk = (const int*)d_in[3];
  const float* Wq = (const float*)d_in[4];
  const float* bq = (const float*)d_in[5];
  const float* Wk = (const float*)d_in[6];
  const float* bk = (const float*)d_in[7];
  const float* Wv = (const float*)d_in[8];
  const float* bv = (const float*)d_in[9];
  const float* Wo = (const float*)d_in[10];
  const float* bo = (const float*)d_in[11];
  char* ws = (char*)d_ws;
  bf16* XQ  = (bf16*)(ws + 0);
  bf16* XK  = (bf16*)(ws + 8388608);
  bf16* XV  = (bf16*)(ws + 16777216);
  bf16* WTQ = (bf16*)(ws + 25165824);
  bf16* WTK = (bf16*)(ws + 27262976);
  bf16* WTV = (bf16*)(ws + 29360128);
  bf16* WTO = (bf16*)(ws + 31457280);
  bf16* QHb = (bf16*)(ws + 33554432);
  bf16* KHb = (bf16*)(ws + 41943040);
  bf16* VTb = (bf16*)(ws + 50331648);   // transposed [bh][d][s]
  bf16* CTX = (bf16*)(ws + 58720256);   // total 64 MiB
  float* out = (float*)d_out;

  prep_kernel<<<dim3(7168), 256, 0, stream>>>(q, k, v, Wq, Wk, Wv, Wo,
                                              XQ, XK, XV, WTQ, WTK, WTV, WTO);
  proj_gemm_kernel<<<dim3(512, 3), 256, 0, stream>>>(XQ, XK, XV, WTQ, WTK, WTV,
                                                     bq, bk, bv, QHb, KHb, VTb);
  attn_kernel<<<dim3(512), 256, 0, stream>>>(QHb, KHb, VTb, msk, CTX);
  out_gemm_kernel<<<dim3(512), 256, 0, stream>>>(CTX, WTO, bo, out);
}

// Round 7
// 268.203 us; speedup vs baseline: 1.1558x; 1.1558x over previous
//
#include <hip/hip_runtime.h>
#include <hip/hip_bf16.h>

// MHA: B=2 S=2048 DM=1024 H=16 DK=64.  All heavy math in bf16 MFMA, fp32 accum.
#define DM 1024
#define SL 2048
#define NH 16
#define DK 64

typedef __bf16 bf16;
typedef __bf16 bf16x8 __attribute__((ext_vector_type(8)));
typedef __bf16 bf16x4 __attribute__((ext_vector_type(4)));
typedef float f32x4 __attribute__((ext_vector_type(4)));
typedef float f32x16 __attribute__((ext_vector_type(16)));
typedef unsigned u32x4 __attribute__((ext_vector_type(4)));

__device__ __forceinline__ void gll16(const void* g, void* l) {
  __builtin_amdgcn_global_load_lds(
      (const __attribute__((address_space(1))) unsigned int*)g,
      (__attribute__((address_space(3))) unsigned int*)l, 16, 0, 0);
}

__device__ __forceinline__ unsigned pk2(float a, float b) {
  unsigned short lo = __builtin_bit_cast(unsigned short, (bf16)a);
  unsigned short hi = __builtin_bit_cast(unsigned short, (bf16)b);
  return (unsigned)lo | ((unsigned)hi << 16);
}

// ---------------- fused prep: fp32->bf16 for q,k,v  +  W^T bf16 for 4 weights ---
__global__ __launch_bounds__(256) void prep_kernel(
    const float* __restrict__ q, const float* __restrict__ k, const float* __restrict__ v,
    const float* __restrict__ Wq, const float* __restrict__ Wk,
    const float* __restrict__ Wv, const float* __restrict__ Wo,
    bf16* __restrict__ xq, bf16* __restrict__ xk, bf16* __restrict__ xv,
    bf16* __restrict__ TQ, bf16* __restrict__ TK, bf16* __restrict__ TV,
    bf16* __restrict__ TO) {
  __shared__ float t[64][65];
  const int bid = blockIdx.x, tid = threadIdx.x;
  if (bid < 6144) {
    const float* src; bf16* dst;
    if (bid < 2048)      { src = q; dst = xq; }
    else if (bid < 4096) { src = k; dst = xk; }
    else                 { src = v; dst = xv; }
    int i = (bid & 2047) * 2048 + tid * 8;
    f32x4 a = *(const f32x4*)(src + i);
    f32x4 b = *(const f32x4*)(src + i + 4);
    bf16x8 o;
    o[0]=(bf16)a[0]; o[1]=(bf16)a[1]; o[2]=(bf16)a[2]; o[3]=(bf16)a[3];
    o[4]=(bf16)b[0]; o[5]=(bf16)b[1]; o[6]=(bf16)b[2]; o[7]=(bf16)b[3];
    *(bf16x8*)(dst + i) = o;
  } else {
    const int wb = bid - 6144;
    const float* W; bf16* T;
    switch (wb >> 8) {
      case 0:  W = Wq; T = TQ; break;
      case 1:  W = Wk; T = TK; break;
      case 2:  W = Wv; T = TV; break;
      default: W = Wo; T = TO; break;
    }
    const int tile = wb & 255;
    const int tx = tile & 15, ty = tile >> 4;   // n-tile tx, k-tile ty
    const int cr = tid >> 4, cc = tid & 15;
    #pragma unroll
    for (int rr = 0; rr < 4; ++rr) {
      int row = rr*16 + cr;
      f32x4 val = *(const f32x4*)(W + (ty*64 + row)*DM + tx*64 + cc*4);
      t[row][cc*4+0] = val[0]; t[row][cc*4+1] = val[1];
      t[row][cc*4+2] = val[2]; t[row][cc*4+3] = val[3];
    }
    __syncthreads();
    #pragma unroll
    for (int rr = 0; rr < 4; ++rr) {
      int nrow = rr*16 + cr;
      bf16x4 o;
      o[0] = (bf16)t[cc*4+0][nrow]; o[1] = (bf16)t[cc*4+1][nrow];
      o[2] = (bf16)t[cc*4+2][nrow]; o[3] = (bf16)t[cc*4+3][nrow];
      *(bf16x4*)(T + (tx*64 + nrow)*DM + ty*64 + cc*4) = o;
    }
  }
}

// ------- 64x128 tile GEMM, BK=64, 3-buffer counted-vmcnt pipeline (T3+T4) -------
// C[m][n] = sum_k A[m][k]*Bt[n][k] (+bias).  4 waves in 2x2 (wave tile 32x64).
// MODE 0: fp32 row-major.  MODE 1: bf16 [bh][s][dk].  MODE 2: bf16 [bh][dk][s].
template<int MODE>
__device__ __forceinline__ void gemm_core(
    const bf16* __restrict__ A, const bf16* __restrict__ Bt, const float* __restrict__ bias,
    bf16* __restrict__ outH, float* __restrict__ outF) {
  const int bid = blockIdx.x;
  const int swz = (bid & 7) * 64 + (bid >> 3);   // XCD-aware bijective (512 blocks)
  const int mt = swz >> 3, nt = swz & 7;
  const int m0 = mt*64, n0 = nt*128;
  __shared__ __attribute__((aligned(16))) bf16 As[3][64*64];
  __shared__ __attribute__((aligned(16))) bf16 Bs[3][128*64];
  const int tid = threadIdx.x, lane = tid & 63, w = tid >> 6;
  const int wm = w >> 1, wn = w & 1;
  f32x4 acc[2][4];
  #pragma unroll
  for (int x = 0; x < 2; ++x)
    #pragma unroll
    for (int y = 0; y < 4; ++y)
      #pragma unroll
      for (int e = 0; e < 4; ++e) acc[x][y][e] = 0.f;

  #define GSTAGE(buf, kt_)                                                 \
    {                                                                      \
      const int k0s = (kt_)*64;                                            \
      _Pragma("unroll")                                                    \
      for (int i = 0; i < 2; ++i) {                                        \
        int idx = (i*4 + w)*64 + lane;                                     \
        int r = idx >> 3;                                                  \
        int s = (idx & 7) ^ (r & 7);                                       \
        gll16(A + (m0 + r)*DM + k0s + s*8, &As[buf][(i*4 + w)*512]);       \
      }                                                                    \
      _Pragma("unroll")                                                    \
      for (int i = 0; i < 4; ++i) {                                        \
        int idx = (i*4 + w)*64 + lane;                                     \
        int r = idx >> 3;                                                  \
        int s = (idx & 7) ^ (r & 7);                                       \
        gll16(Bt + (n0 + r)*DM + k0s + s*8, &Bs[buf][(i*4 + w)*512]);      \
      }                                                                    \
    }

  #define GCOMPUTE(cb)                                                             \
    {                                                                              \
      bf16x8 bfr[4][2];                                                            \
      _Pragma("unroll")                                                            \
      for (int ni = 0; ni < 4; ++ni) {                                             \
        int row = wn*64 + ni*16 + (lane & 15);                                     \
        _Pragma("unroll")                                                          \
        for (int c = 0; c < 2; ++c) {                                              \
          int slot = (lane >> 4) + c*4;                                            \
          bfr[ni][c] = *(const bf16x8*)&Bs[cb][row*64 + ((slot ^ (row & 7)) << 3)];\
        }                                                                          \
      }                                                                            \
      __builtin_amdgcn_s_setprio(1);                                               \
      _Pragma("unroll")                                                            \
      for (int mi = 0; mi < 2; ++mi) {                                             \
        int row = wm*32 + mi*16 + (lane & 15);                                     \
        bf16x8 a0 = *(const bf16x8*)&As[cb][row*64 + ((((lane >> 4)    ) ^ (row & 7)) << 3)]; \
        bf16x8 a1 = *(const bf16x8*)&As[cb][row*64 + ((((lane >> 4) + 4) ^ (row & 7)) << 3)]; \
        _Pragma("unroll")                                                          \
        for (int ni = 0; ni < 4; ++ni) {                                           \
          acc[mi][ni] = __builtin_amdgcn_mfma_f32_16x16x32_bf16(a0, bfr[ni][0], acc[mi][ni], 0, 0, 0); \
          acc[mi][ni] = __builtin_amdgcn_mfma_f32_16x16x32_bf16(a1, bfr[ni][1], acc[mi][ni], 0, 0, 0); \
        }                                                                          \
      }                                                                            \
      __builtin_amdgcn_s_setprio(0);                                               \
    }

  GSTAGE(0, 0);
  __syncthreads();                 // one-time full drain (tile 0 landed)
  int cur = 0;
  for (int kt = 0; kt < 15; ++kt) {
    int nxt = cur + 1; if (nxt == 3) nxt = 0;
    GSTAGE(nxt, kt + 1);           // tile kt+1 flies across the barrier
    asm volatile("s_waitcnt vmcnt(6)" ::: "memory");   // tile kt done; kt+1 in flight
    __builtin_amdgcn_s_barrier();
    GCOMPUTE(cur);
    cur = nxt;
  }
  asm volatile("s_waitcnt vmcnt(0)" ::: "memory");
  __builtin_amdgcn_s_barrier();
  GCOMPUTE(cur);                   // kt = 15
  #undef GSTAGE
  #undef GCOMPUTE

  #pragma unroll
  for (int ni = 0; ni < 4; ++ni) {
    int n = n0 + wn*64 + ni*16 + (lane & 15);
    float bv = bias[n];
    #pragma unroll
    for (int mi = 0; mi < 2; ++mi) {
      int mb = m0 + wm*32 + mi*16 + ((lane >> 4) << 2);
      if (MODE == 2) {
        int bb = mb >> 11, ss = mb & 2047, hh = n >> 6, dd = n & 63;
        bf16x4 o;
        #pragma unroll
        for (int j = 0; j < 4; ++j) o[j] = (bf16)(acc[mi][ni][j] + bv);
        *(bf16x4*)&outH[(((bb << 4) + hh)*DK + dd)*SL + ss] = o;
      } else {
        #pragma unroll
        for (int j = 0; j < 4; ++j) {
          int m = mb + j;
          float val = acc[mi][ni][j] + bv;
          if (MODE == 1) {
            int bb = m >> 11, ss = m & 2047, hh = n >> 6, dd = n & 63;
            outH[(((bb << 4) + hh)*SL + ss)*DK + dd] = (bf16)val;
          } else {
            outF[m*DM + n] = val;
          }
        }
      }
    }
  }
}

__global__ __launch_bounds__(256, 2) void proj_gemm_kernel(
    const bf16* XQ, const bf16* XK, const bf16* XV,
    const bf16* WTQp, const bf16* WTKp, const bf16* WTVp,
    const float* bq, const float* bk, const float* bv,
    bf16* QHp, bf16* KHp, bf16* VTp) {
  if (blockIdx.y == 0)      gemm_core<1>(XQ, WTQp, bq, QHp, nullptr);
  else if (blockIdx.y == 1) gemm_core<1>(XK, WTKp, bk, KHp, nullptr);
  else                      gemm_core<2>(XV, WTVp, bv, VTp, nullptr);
}

__global__ __launch_bounds__(256, 2) void out_gemm_kernel(
    const bf16* CTXp, const bf16* WTOp, const float* bo, float* out) {
  gemm_core<0>(CTXp, WTOp, bo, nullptr, out);
}

// ---------------- flash attention, swapped-QK^T, 32x32x16 MFMA ----------------
// 4 waves x 32-query strips (QBLK=128), KBLK=64, 3-buffer counted-vmcnt pipeline,
// V pre-transposed (VT[bh][d][s]), in-register P redistribution (static indices),
// defer-max, log2-unit scores, mask bias in LDS (built once), XCD-bh clustering.
__global__ __launch_bounds__(256, 2) void attn_kernel(
    const bf16* __restrict__ QHp, const bf16* __restrict__ KHp,
    const bf16* __restrict__ VTp, const int* __restrict__ msk,
    bf16* __restrict__ CTXp) {
  // bijective XCD swizzle over 512 blocks: xcd owns bh in [4*xcd, 4*xcd+4)
  const int d = blockIdx.x;
  const int xcd = d & 7, rr = d >> 3;
  const int bh = xcd*4 + (rr >> 4);
  const int qt = rr & 15;
  const int b = bh >> 4, h = bh & 15;
  const int q0 = qt * 128;
  const bf16* Qp  = QHp + bh * SL * DK;
  const bf16* Kp  = KHp + bh * SL * DK;
  const bf16* Vtp = VTp + bh * SL * DK;   // [d][s]
  const int* mp = msk + b * SL;
  __shared__ __attribute__((aligned(16))) bf16 Ks[3][64*64];   // [key][d] swizzled
  __shared__ __attribute__((aligned(16))) bf16 Vts[3][64*64];  // [d][key] swizzled
  __shared__ __attribute__((aligned(16))) float mAdd[SL];      // log2-unit bias
  const int tid = threadIdx.x, lane = tid & 63, w = tid >> 6;
  const int hi = lane >> 5, l5 = lane & 31;
  const float SCL2E = 0.18033688f;   // 0.125 * log2(e)

  // mask -> additive log2-bias into LDS, once (steady loop then has 0 extra VMEM)
  {
    int i0 = tid * 8;
    int4 a = *(const int4*)(mp + i0);
    int4 c = *(const int4*)(mp + i0 + 4);
    f32x4 oa, oc;
    oa[0] = a.x ? 0.f : -1.4426950e9f; oa[1] = a.y ? 0.f : -1.4426950e9f;
    oa[2] = a.z ? 0.f : -1.4426950e9f; oa[3] = a.w ? 0.f : -1.4426950e9f;
    oc[0] = c.x ? 0.f : -1.4426950e9f; oc[1] = c.y ? 0.f : -1.4426950e9f;
    oc[2] = c.z ? 0.f : -1.4426950e9f; oc[3] = c.w ? 0.f : -1.4426950e9f;
    *(f32x4*)&mAdd[i0] = oa;
    *(f32x4*)&mAdd[i0 + 4] = oc;
  }

  // Q fragments (regs whole kernel): B-operand col = q = l5
  bf16x8 qf[4];
  {
    const bf16* qr = Qp + (q0 + w*32 + l5)*DK + hi*8;
    #pragma unroll
    for (int c = 0; c < 4; ++c) qf[c] = *(const bf16x8*)(qr + c*16);
  }
  f32x16 o0, o1;
  #pragma unroll
  for (int e = 0; e < 16; ++e) { o0[e] = 0.f; o1[e] = 0.f; }
  float m_run = -1e30f, l_run = 0.f;   // m_run in log2 units

  #define STAGE(buf, kt_)                                                  \
    {                                                                      \
      const int k0s = (kt_)*64;                                            \
      _Pragma("unroll")                                                    \
      for (int i = 0; i < 2; ++i) {                                        \
        int idx = (i*4 + w)*64 + lane;                                     \
        int r = idx >> 3;                                                  \
        int s = (idx & 7) ^ (r & 7);                                       \
        gll16(Kp + (k0s + r)*DK + s*8, &Ks[buf][(i*4 + w)*512]);           \
      }                                                                    \
      _Pragma("unroll")                                                    \
      for (int i = 0; i < 2; ++i) {                                        \
        int idx = (i*4 + w)*64 + lane;                                     \
        int r = idx >> 3;                                                  \
        int s = (idx & 7) ^ (r & 7);                                       \
        gll16(Vtp + r*SL + k0s + s*8, &Vts[buf][(i*4 + w)*512]);           \
      }                                                                    \
    }

  // one tile of work: QK^T -> online softmax -> PV, on buffer cb, key-offset k0
  #define ATILE(cb, k0)                                                          \
    {                                                                            \
      f32x16 s0, s1;                                                             \
      _Pragma("unroll")                                                          \
      for (int e = 0; e < 16; ++e) { s0[e] = 0.f; s1[e] = 0.f; }                 \
      __builtin_amdgcn_s_setprio(1);                                             \
      _Pragma("unroll")                                                          \
      for (int c = 0; c < 4; ++c) {                                              \
        int sl = 2*c + hi;                                                       \
        int r0 = l5, r1 = 32 + l5;                                               \
        bf16x8 kf0 = *(const bf16x8*)&Ks[cb][r0*64 + ((sl ^ (r0 & 7)) << 3)];    \
        bf16x8 kf1 = *(const bf16x8*)&Ks[cb][r1*64 + ((sl ^ (r1 & 7)) << 3)];    \
        s0 = __builtin_amdgcn_mfma_f32_32x32x16_bf16(kf0, qf[c], s0, 0, 0, 0);   \
        s1 = __builtin_amdgcn_mfma_f32_32x32x16_bf16(kf1, qf[c], s1, 0, 0, 0);   \
      }                                                                          \
      __builtin_amdgcn_s_setprio(0);                                             \
      float pv_[32];                                                             \
      float mtv0 = -1e30f, mtv1 = -1e30f, mtv2 = -1e30f, mtv3 = -1e30f;          \
      _Pragma("unroll")                                                          \
      for (int half = 0; half < 2; ++half) {                                     \
        _Pragma("unroll")                                                        \
        for (int qd = 0; qd < 4; ++qd) {                                         \
          f32x4 ma = *(const f32x4*)&mAdd[(k0) + half*32 + qd*8 + hi*4];         \
          _Pragma("unroll")                                                      \
          for (int j = 0; j < 4; ++j) {                                          \
            float val = (half ? s1[qd*4+j] : s0[qd*4+j]) * SCL2E + ma[j];        \
            pv_[half*16 + qd*4 + j] = val;                                       \
            if (j == 0) mtv0 = fmaxf(mtv0, val);                                 \
            else if (j == 1) mtv1 = fmaxf(mtv1, val);                            \
            else if (j == 2) mtv2 = fmaxf(mtv2, val);                            \
            else mtv3 = fmaxf(mtv3, val);                                        \
          }                                                                      \
        }                                                                        \
      }                                                                          \
      float mt = fmaxf(fmaxf(mtv0, mtv1), fmaxf(mtv2, mtv3));                    \
      mt = fmaxf(mt, __shfl_xor(mt, 32));                                        \
      if (!__all(mt - m_run <= 11.5f)) {                                         \
        float mnew = fmaxf(m_run, mt);                                           \
        float sf = exp2f(m_run - mnew);                                          \
        _Pragma("unroll")                                                        \
        for (int reg = 0; reg < 16; ++reg) {                                     \
          int crow = (reg & 3) + ((reg >> 2) << 3) + (hi << 2);                  \
          float s_ = __shfl(sf, crow);                                           \
          o0[reg] *= s_; o1[reg] *= s_;                                          \
        }                                                                        \
        l_run *= sf;                                                             \
        m_run = mnew;                                                            \
      }                                                                          \
      float ls0 = 0.f, ls1 = 0.f, ls2 = 0.f, ls3 = 0.f;                          \
      _Pragma("unroll")                                                          \
      for (int t = 0; t < 32; ++t) {                                             \
        float p = exp2f(pv_[t] - m_run);                                         \
        pv_[t] = p;                                                              \
        if ((t & 3) == 0) ls0 += p;                                              \
        else if ((t & 3) == 1) ls1 += p;                                         \
        else if ((t & 3) == 2) ls2 += p;                                         \
        else ls3 += p;                                                           \
      }                                                                          \
      float lsum = (ls0 + ls1) + (ls2 + ls3);                                    \
      lsum += __shfl_xor(lsum, 32);                                              \
      l_run += lsum;                                                             \
      _Pragma("unroll")                                                          \
      for (int c = 0; c < 4; ++c) {                                              \
        const int half_c = c >> 1;                                               \
        const int iA = half_c*16 + (((2*c)    ) & 3)*4;                          \
        const int iB = half_c*16 + (((2*c) + 1) & 3)*4;                          \
        unsigned wA0 = pk2(pv_[iA],   pv_[iA+1]);                                \
        unsigned wA1 = pk2(pv_[iA+2], pv_[iA+3]);                                \
        unsigned wB0 = pk2(pv_[iB],   pv_[iB+1]);                                \
        unsigned wB1 = pk2(pv_[iB+2], pv_[iB+3]);                                \
        unsigned ow0 = hi ? wB0 : wA0, ow1 = hi ? wB1 : wA1;                     \
        unsigned xw0 = hi ? wA0 : wB0, xw1 = hi ? wA1 : wB1;                     \
        unsigned yw0 = __shfl_xor(xw0, 32);                                      \
        unsigned yw1 = __shfl_xor(xw1, 32);                                      \
        u32x4 uu;                                                                \
        uu[0] = hi ? yw0 : ow0;                                                  \
        uu[1] = hi ? yw1 : ow1;                                                  \
        uu[2] = hi ? ow0 : yw0;                                                  \
        uu[3] = hi ? ow1 : yw1;                                                  \
        bf16x8 pa = __builtin_bit_cast(bf16x8, uu);                              \
        int sl = 2*c + hi;                                                       \
        int r0 = l5, r1 = 32 + l5;                                               \
        bf16x8 vf0 = *(const bf16x8*)&Vts[cb][r0*64 + ((sl ^ (r0 & 7)) << 3)];   \
        bf16x8 vf1 = *(const bf16x8*)&Vts[cb][r1*64 + ((sl ^ (r1 & 7)) << 3)];   \
        __builtin_amdgcn_s_setprio(1);                                           \
        o0 = __builtin_amdgcn_mfma_f32_32x32x16_bf16(pa, vf0, o0, 0, 0, 0);      \
        o1 = __builtin_amdgcn_mfma_f32_32x32x16_bf16(pa, vf1, o1, 0, 0, 0);      \
        __builtin_amdgcn_s_setprio(0);                                           \
      }                                                                          \
    }

  STAGE(0, 0);
  __syncthreads();                 // one-time full drain (tile 0 + mask LDS)
  int cur = 0;
  for (int kt = 0; kt < 31; ++kt) {
    int nxt = cur + 1; if (nxt == 3) nxt = 0;
    STAGE(nxt, kt + 1);            // tile kt+1 flies across the barrier
    asm volatile("s_waitcnt vmcnt(4)" ::: "memory");   // tile kt done; kt+1 in flight
    __builtin_amdgcn_s_barrier();
    ATILE(cur, kt*64);
    cur = nxt;
  }
  asm volatile("s_waitcnt vmcnt(0)" ::: "memory");
  __builtin_amdgcn_s_barrier();
  ATILE(cur, 31*64);
  #undef STAGE
  #undef ATILE

  // epilogue
  float inv = 1.f / l_run;
  const int sbase = (b * SL) * DM + h * DK;
  #pragma unroll
  for (int reg = 0; reg < 16; ++reg) {
    int crow = (reg & 3) + ((reg >> 2) << 3) + (hi << 2);
    float iv = __shfl(inv, crow);
    int srow = q0 + w*32 + crow;
    CTXp[sbase + srow*DM + l5]      = (bf16)(o0[reg] * iv);
    CTXp[sbase + srow*DM + 32 + l5] = (bf16)(o1[reg] * iv);
  }
}

extern "C" void kernel_launch(void* const* d_in, const int* in_sizes, int n_in,
                              void* d_out, int out_size, void* d_ws, size_t ws_size,
                              hipStream_t stream) {
  const float* q  = (const float*)d_in[0];
  const float* k  = (const float*)d_in[1];
  const float* v  = (const float*)d_in[2];
  const int*  msk = (const int*)d_in[3];
  const float* Wq = (const float*)d_in[4];
  const float* bq = (const float*)d_in[5];
  const float* Wk = (const float*)d_in[6];
  const float* bk = (const float*)d_in[7];
  const float* Wv = (const float*)d_in[8];
  const float* bv = (const float*)d_in[9];
  const float* Wo = (const float*)d_in[10];
  const float* bo = (const float*)d_in[11];
  char* ws = (char*)d_ws;
  bf16* XQ  = (bf16*)(ws + 0);
  bf16* XK  = (bf16*)(ws + 8388608);
  bf16* XV  = (bf16*)(ws + 16777216);
  bf16* WTQ = (bf16*)(ws + 25165824);
  bf16* WTK = (bf16*)(ws + 27262976);
  bf16* WTV = (bf16*)(ws + 29360128);
  bf16* WTO = (bf16*)(ws + 31457280);
  bf16* QHb = (bf16*)(ws + 33554432);
  bf16* KHb = (bf16*)(ws + 41943040);
  bf16* VTb = (bf16*)(ws + 50331648);   // transposed [bh][d][s]
  bf16* CTX = (bf16*)(ws + 58720256);   // total 64 MiB
  float* out = (float*)d_out;

  prep_kernel<<<dim3(7168), 256, 0, stream>>>(q, k, v, Wq, Wk, Wv, Wo,
                                              XQ, XK, XV, WTQ, WTK, WTV, WTO);
  proj_gemm_kernel<<<dim3(512, 3), 256, 0, stream>>>(XQ, XK, XV, WTQ, WTK, WTV,
                                                     bq, bk, bv, QHb, KHb, VTb);
  attn_kernel<<<dim3(512), 256, 0, stream>>>(QHb, KHb, VTb, msk, CTX);
  out_gemm_kernel<<<dim3(512), 256, 0, stream>>>(CTX, WTO, bo, out);
}

// Round 10
// 230.392 us; speedup vs baseline: 1.3455x; 1.1641x over previous
//
#include <hip/hip_runtime.h>
#include <hip/hip_bf16.h>

// MHA: B=2 S=2048 DM=1024 H=16 DK=64.  bf16 MFMA, fp32 accum, key compaction.
#define DM 1024
#define SL 2048
#define NH 16
#define DK 64

typedef __bf16 bf16;
typedef __bf16 bf16x8 __attribute__((ext_vector_type(8)));
typedef __bf16 bf16x4 __attribute__((ext_vector_type(4)));
typedef float f32x4 __attribute__((ext_vector_type(4)));
typedef float f32x16 __attribute__((ext_vector_type(16)));
typedef unsigned u32x4 __attribute__((ext_vector_type(4)));

__device__ __forceinline__ void gll16(const void* g, void* l) {
  __builtin_amdgcn_global_load_lds(
      (const __attribute__((address_space(1))) unsigned int*)g,
      (__attribute__((address_space(3))) unsigned int*)l, 16, 0, 0);
}

__device__ __forceinline__ unsigned pk2(float a, float b) {
  unsigned short lo = __builtin_bit_cast(unsigned short, (bf16)a);
  unsigned short hi = __builtin_bit_cast(unsigned short, (bf16)b);
  return (unsigned)lo | ((unsigned)hi << 16);
}

// -------- mask scan: per batch, list of valid key indices + count ----------
__global__ __launch_bounds__(256) void mask_scan_kernel(
    const int* __restrict__ msk, int* __restrict__ gidx, int* __restrict__ nvp) {
  const int b = blockIdx.x, tid = threadIdx.x;
  const int* mp = msk + b * SL;
  __shared__ int ssum[256];
  int loc[8]; int cnt = 0;
  #pragma unroll
  for (int j = 0; j < 8; ++j) { loc[j] = (mp[tid*8 + j] != 0); cnt += loc[j]; }
  ssum[tid] = cnt;
  __syncthreads();
  for (int off = 1; off < 256; off <<= 1) {
    int v = ssum[tid];
    int vv = (tid >= off) ? ssum[tid - off] : 0;
    __syncthreads();
    ssum[tid] = v + vv;
    __syncthreads();
  }
  int base = ssum[tid] - cnt;   // exclusive prefix
  #pragma unroll
  for (int j = 0; j < 8; ++j) {
    if (loc[j]) gidx[b*SL + base++] = tid*8 + j;
  }
  if (tid == 255) nvp[b] = ssum[255];
}

// -------- fused prep: q convert + k/v COMPACTED gather-convert + W^T ----------
__global__ __launch_bounds__(256) void prep_kernel(
    const float* __restrict__ q, const float* __restrict__ k, const float* __restrict__ v,
    const float* __restrict__ Wq, const float* __restrict__ Wk,
    const float* __restrict__ Wv, const float* __restrict__ Wo,
    bf16* __restrict__ xq, bf16* __restrict__ xk, bf16* __restrict__ xv,
    bf16* __restrict__ TQ, bf16* __restrict__ TK, bf16* __restrict__ TV,
    bf16* __restrict__ TO,
    const int* __restrict__ gidx, const int* __restrict__ nvp) {
  __shared__ float t[64][65];
  const int bid = blockIdx.x, tid = threadIdx.x;
  if (bid < 2048) {                       // q: straight convert
    int i = bid * 2048 + tid * 8;
    f32x4 a = *(const f32x4*)(q + i);
    f32x4 b2 = *(const f32x4*)(q + i + 4);
    bf16x8 o;
    o[0]=(bf16)a[0]; o[1]=(bf16)a[1]; o[2]=(bf16)a[2]; o[3]=(bf16)a[3];
    o[4]=(bf16)b2[0]; o[5]=(bf16)b2[1]; o[6]=(bf16)b2[2]; o[7]=(bf16)b2[3];
    *(bf16x8*)(xq + i) = o;
  } else if (bid < 6144) {                // k/v: gather valid rows, zero pads
    const int isV = (bid >= 4096);
    const float* src = isV ? v : k;
    bf16* dst = isV ? xv : xk;
    const int orow = ((bid - (isV ? 4096 : 2048)) << 1) + (tid >> 7);  // 0..4095
    const int bb = orow >> 11, j = orow & 2047;
    const int col = (tid & 127) * 8;
    bf16x8 o;
    if (j < nvp[bb]) {
      int sr = gidx[bb*SL + j];
      const float* rp = src + (bb*SL + sr)*DM + col;
      f32x4 a = *(const f32x4*)rp;
      f32x4 b2 = *(const f32x4*)(rp + 4);
      o[0]=(bf16)a[0]; o[1]=(bf16)a[1]; o[2]=(bf16)a[2]; o[3]=(bf16)a[3];
      o[4]=(bf16)b2[0]; o[5]=(bf16)b2[1]; o[6]=(bf16)b2[2]; o[7]=(bf16)b2[3];
    } else {
      #pragma unroll
      for (int e = 0; e < 8; ++e) o[e] = (bf16)0.f;
    }
    *(bf16x8*)(dst + orow*DM + col) = o;
  } else {                                // weights: transpose + convert
    const int wb = bid - 6144;
    const float* W; bf16* T;
    switch (wb >> 8) {
      case 0:  W = Wq; T = TQ; break;
      case 1:  W = Wk; T = TK; break;
      case 2:  W = Wv; T = TV; break;
      default: W = Wo; T = TO; break;
    }
    const int tile = wb & 255;
    const int tx = tile & 15, ty = tile >> 4;
    const int cr = tid >> 4, cc = tid & 15;
    #pragma unroll
    for (int rr = 0; rr < 4; ++rr) {
      int row = rr*16 + cr;
      f32x4 val = *(const f32x4*)(W + (ty*64 + row)*DM + tx*64 + cc*4);
      t[row][cc*4+0] = val[0]; t[row][cc*4+1] = val[1];
      t[row][cc*4+2] = val[2]; t[row][cc*4+3] = val[3];
    }
    __syncthreads();
    #pragma unroll
    for (int rr = 0; rr < 4; ++rr) {
      int nrow = rr*16 + cr;
      bf16x4 o;
      o[0] = (bf16)t[cc*4+0][nrow]; o[1] = (bf16)t[cc*4+1][nrow];
      o[2] = (bf16)t[cc*4+2][nrow]; o[3] = (bf16)t[cc*4+3][nrow];
      *(bf16x4*)(T + (tx*64 + nrow)*DM + ty*64 + cc*4) = o;
    }
  }
}

// --- 64x128 GEMM, BK=64, 3-buffer depth-2 counted-vmcnt pipeline (T3+T4) ------
// Shared memory is allocated ONCE in the kernel and passed in (avoids the
// per-instantiation duplication that blew LDS to 144KB in R7).
template<int MODE>
__device__ __forceinline__ void gemm_core(
    const bf16* __restrict__ A, const bf16* __restrict__ Bt, const float* __restrict__ bias,
    bf16* __restrict__ outH, float* __restrict__ outF,
    bf16* As, bf16* Bs) {
  const int bid = blockIdx.x;
  const int swz = (bid & 7) * 64 + (bid >> 3);   // XCD-aware bijective (512 blocks)
  const int mt = swz >> 3, nt = swz & 7;
  const int m0 = mt*64, n0 = nt*128;
  const int tid = threadIdx.x, lane = tid & 63, w = tid >> 6;
  const int wm = w >> 1, wn = w & 1;
  f32x4 acc[2][4];
  #pragma unroll
  for (int x = 0; x < 2; ++x)
    #pragma unroll
    for (int y = 0; y < 4; ++y)
      #pragma unroll
      for (int e = 0; e < 4; ++e) acc[x][y][e] = 0.f;

  #define GSTAGE(buf, kt_)                                                  \
    {                                                                       \
      const int k0s = (kt_)*64;                                             \
      _Pragma("unroll")                                                     \
      for (int i = 0; i < 2; ++i) {                                         \
        int idx = (i*4 + w)*64 + lane;                                      \
        int r = idx >> 3;                                                   \
        int s = (idx & 7) ^ (r & 7);                                        \
        gll16(A + (m0 + r)*DM + k0s + s*8, &As[(buf)*4096 + (i*4 + w)*512]);\
      }                                                                     \
      _Pragma("unroll")                                                     \
      for (int i = 0; i < 4; ++i) {                                         \
        int idx = (i*4 + w)*64 + lane;                                      \
        int r = idx >> 3;                                                   \
        int s = (idx & 7) ^ (r & 7);                                        \
        gll16(Bt + (n0 + r)*DM + k0s + s*8, &Bs[(buf)*8192 + (i*4 + w)*512]);\
      }                                                                     \
    }

  #define GCOMPUTE(cb)                                                              \
    {                                                                               \
      bf16x8 bfr[4][2];                                                             \
      _Pragma("unroll")                                                             \
      for (int ni = 0; ni < 4; ++ni) {                                              \
        int row = wn*64 + ni*16 + (lane & 15);                                      \
        _Pragma("unroll")                                                           \
        for (int c = 0; c < 2; ++c) {                                               \
          int slot = (lane >> 4) + c*4;                                             \
          bfr[ni][c] = *(const bf16x8*)&Bs[(cb)*8192 + row*64 + ((slot ^ (row & 7)) << 3)]; \
        }                                                                           \
      }                                                                             \
      __builtin_amdgcn_s_setprio(1);                                                \
      _Pragma("unroll")                                                             \
      for (int mi = 0; mi < 2; ++mi) {                                              \
        int row = wm*32 + mi*16 + (lane & 15);                                      \
        bf16x8 a0 = *(const bf16x8*)&As[(cb)*4096 + row*64 + ((((lane >> 4)    ) ^ (row & 7)) << 3)]; \
        bf16x8 a1 = *(const bf16x8*)&As[(cb)*4096 + row*64 + ((((lane >> 4) + 4) ^ (row & 7)) << 3)]; \
        _Pragma("unroll")                                                           \
        for (int ni = 0; ni < 4; ++ni) {                                            \
          acc[mi][ni] = __builtin_amdgcn_mfma_f32_16x16x32_bf16(a0, bfr[ni][0], acc[mi][ni], 0, 0, 0); \
          acc[mi][ni] = __builtin_amdgcn_mfma_f32_16x16x32_bf16(a1, bfr[ni][1], acc[mi][ni], 0, 0, 0); \
        }                                                                           \
      }                                                                             \
      __builtin_amdgcn_s_setprio(0);                                                \
    }

  GSTAGE(0, 0);
  GSTAGE(1, 1);
  __syncthreads();                 // one-time full drain (tiles 0,1 landed)
  int cur = 0;
  for (int kt = 0; kt < 16; ++kt) {
    // wait tile kt (leave tile kt+1's 6 loads in flight), then barrier —
    // single asm so no memory op can slip between the wait and the barrier.
    asm volatile("s_waitcnt vmcnt(6)\n\ts_barrier" ::: "memory");
    int nb = cur + 2; if (nb >= 3) nb -= 3;
    int kts = kt + 2; if (kts > 15) kts = 15;   // clamped dup: uniform vmcnt math
    GSTAGE(nb, kts);
    GCOMPUTE(cur);
    ++cur; if (cur == 3) cur = 0;
  }
  asm volatile("s_waitcnt vmcnt(0)" ::: "memory");   // drain dups before exit
  #undef GSTAGE
  #undef GCOMPUTE

  #pragma unroll
  for (int ni = 0; ni < 4; ++ni) {
    int n = n0 + wn*64 + ni*16 + (lane & 15);
    float bv = bias[n];
    #pragma unroll
    for (int mi = 0; mi < 2; ++mi) {
      int mb = m0 + wm*32 + mi*16 + ((lane >> 4) << 2);
      if (MODE == 2) {
        int bb = mb >> 11, ss = mb & 2047, hh = n >> 6, dd = n & 63;
        bf16x4 o;
        #pragma unroll
        for (int j = 0; j < 4; ++j) o[j] = (bf16)(acc[mi][ni][j] + bv);
        *(bf16x4*)&outH[(((bb << 4) + hh)*DK + dd)*SL + ss] = o;
      } else {
        #pragma unroll
        for (int j = 0; j < 4; ++j) {
          int m = mb + j;
          float val = acc[mi][ni][j] + bv;
          if (MODE == 1) {
            int bb = m >> 11, ss = m & 2047, hh = n >> 6, dd = n & 63;
            outH[(((bb << 4) + hh)*SL + ss)*DK + dd] = (bf16)val;
          } else {
            outF[m*DM + n] = val;
          }
        }
      }
    }
  }
}

__global__ __launch_bounds__(256, 2) void proj_gemm_kernel(
    const bf16* XQ, const bf16* XK, const bf16* XV,
    const bf16* WTQp, const bf16* WTKp, const bf16* WTVp,
    const float* bq, const float* bk, const float* bv,
    bf16* QHp, bf16* KHp, bf16* VTp) {
  __shared__ __attribute__((aligned(16))) bf16 As[3*64*64];
  __shared__ __attribute__((aligned(16))) bf16 Bs[3*128*64];
  if (blockIdx.y == 0)      gemm_core<1>(XQ, WTQp, bq, QHp, nullptr, As, Bs);
  else if (blockIdx.y == 1) gemm_core<1>(XK, WTKp, bk, KHp, nullptr, As, Bs);
  else                      gemm_core<2>(XV, WTVp, bv, VTp, nullptr, As, Bs);
}

__global__ __launch_bounds__(256, 2) void out_gemm_kernel(
    const bf16* CTXp, const bf16* WTOp, const float* bo, float* out) {
  __shared__ __attribute__((aligned(16))) bf16 As[3*64*64];
  __shared__ __attribute__((aligned(16))) bf16 Bs[3*128*64];
  gemm_core<0>(CTXp, WTOp, bo, nullptr, out, As, Bs);
}

// ------------- flash attention over COMPACTED keys, 32x32x16 MFMA -------------
// 4 waves x 32-query strips, KBLK=64, 3-buffer depth-2 counted-vmcnt pipeline,
// V pre-transposed (VT[bh][d][s]), in-register P redistribution, defer-max,
// log2-unit scores, in-register pad masking (key<nv), XCD-bh clustering.
__global__ __launch_bounds__(256, 2) void attn_kernel(
    const bf16* __restrict__ QHp, const bf16* __restrict__ KHp,
    const bf16* __restrict__ VTp, const int* __restrict__ nvp,
    bf16* __restrict__ CTXp) {
  const int d = blockIdx.x;
  const int xcd = d & 7, rr = d >> 3;
  const int bh = xcd*4 + (rr >> 4);
  const int qt = rr & 15;
  const int b = bh >> 4, h = bh & 15;
  const int q0 = qt * 128;
  const bf16* Qp  = QHp + bh * SL * DK;
  const bf16* Kp  = KHp + bh * SL * DK;
  const bf16* Vtp = VTp + bh * SL * DK;   // [d][s]
  __shared__ __attribute__((aligned(16))) bf16 Ks[3][64*64];   // [key][d] swizzled
  __shared__ __attribute__((aligned(16))) bf16 Vts[3][64*64];  // [d][key] swizzled
  const int tid = threadIdx.x, lane = tid & 63, w = tid >> 6;
  const int hi = lane >> 5, l5 = lane & 31;
  const float SCL2E = 0.18033688f;   // 0.125 * log2(e)

  const int nv = nvp[b];
  int ntile = (nv + 63) >> 6; if (ntile < 1) ntile = 1;

  // Q fragments (regs whole kernel): B-operand col = q = l5
  bf16x8 qf[4];
  {
    const bf16* qr = Qp + (q0 + w*32 + l5)*DK + hi*8;
    #pragma unroll
    for (int c = 0; c < 4; ++c) qf[c] = *(const bf16x8*)(qr + c*16);
  }
  f32x16 o0, o1;
  #pragma unroll
  for (int e = 0; e < 16; ++e) { o0[e] = 0.f; o1[e] = 0.f; }
  float m_run = -1e30f, l_run = 0.f;   // m_run in log2 units

  #define STAGE(buf, kt_)                                                  \
    {                                                                      \
      const int k0s = (kt_)*64;                                            \
      _Pragma("unroll")                                                    \
      for (int i = 0; i < 2; ++i) {                                        \
        int idx = (i*4 + w)*64 + lane;                                     \
        int r = idx >> 3;                                                  \
        int s = (idx & 7) ^ (r & 7);                                       \
        gll16(Kp + (k0s + r)*DK + s*8, &Ks[buf][(i*4 + w)*512]);           \
      }                                                                    \
      _Pragma("unroll")                                                    \
      for (int i = 0; i < 2; ++i) {                                        \
        int idx = (i*4 + w)*64 + lane;                                     \
        int r = idx >> 3;                                                  \
        int s = (idx & 7) ^ (r & 7);                                       \
        gll16(Vtp + r*SL + k0s + s*8, &Vts[buf][(i*4 + w)*512]);           \
      }                                                                    \
    }

  #define ATILE(cb, k0)                                                          \
    {                                                                            \
      f32x16 s0, s1;                                                             \
      _Pragma("unroll")                                                          \
      for (int e = 0; e < 16; ++e) { s0[e] = 0.f; s1[e] = 0.f; }                 \
      __builtin_amdgcn_s_setprio(1);                                             \
      _Pragma("unroll")                                                          \
      for (int c = 0; c < 4; ++c) {                                              \
        int sl = 2*c + hi;                                                       \
        int r0 = l5, r1 = 32 + l5;                                               \
        bf16x8 kf0 = *(const bf16x8*)&Ks[cb][r0*64 + ((sl ^ (r0 & 7)) << 3)];    \
        bf16x8 kf1 = *(const bf16x8*)&Ks[cb][r1*64 + ((sl ^ (r1 & 7)) << 3)];    \
        s0 = __builtin_amdgcn_mfma_f32_32x32x16_bf16(kf0, qf[c], s0, 0, 0, 0);   \
        s1 = __builtin_amdgcn_mfma_f32_32x32x16_bf16(kf1, qf[c], s1, 0, 0, 0);   \
      }                                                                          \
      __builtin_amdgcn_s_setprio(0);                                             \
      float pv_[32];                                                             \
      float mtv0 = -1e30f, mtv1 = -1e30f, mtv2 = -1e30f, mtv3 = -1e30f;          \
      _Pragma("unroll")                                                          \
      for (int half = 0; half < 2; ++half) {                                     \
        _Pragma("unroll")                                                        \
        for (int qd = 0; qd < 4; ++qd) {                                         \
          _Pragma("unroll")                                                      \
          for (int j = 0; j < 4; ++j) {                                          \
            float val = (half ? s1[qd*4+j] : s0[qd*4+j]) * SCL2E;                \
            int key = (k0) + half*32 + qd*8 + hi*4 + j;                          \
            val = (key < nv) ? val : -1.0e9f;                                    \
            pv_[half*16 + qd*4 + j] = val;                                       \
            if (j == 0) mtv0 = fmaxf(mtv0, val);                                 \
            else if (j == 1) mtv1 = fmaxf(mtv1, val);                            \
            else if (j == 2) mtv2 = fmaxf(mtv2, val);                            \
            else mtv3 = fmaxf(mtv3, val);                                        \
          }                                                                      \
        }                                                                        \
      }                                                                          \
      float mt = fmaxf(fmaxf(mtv0, mtv1), fmaxf(mtv2, mtv3));                    \
      mt = fmaxf(mt, __shfl_xor(mt, 32));                                        \
      if (!__all(mt - m_run <= 11.5f)) {                                         \
        float mnew = fmaxf(m_run, mt);                                           \
        float sf = exp2f(m_run - mnew);                                          \
        _Pragma("unroll")                                                        \
        for (int reg = 0; reg < 16; ++reg) {                                     \
          int crow = (reg & 3) + ((reg >> 2) << 3) + (hi << 2);                  \
          float s_ = __shfl(sf, crow);                                           \
          o0[reg] *= s_; o1[reg] *= s_;                                          \
        }                                                                        \
        l_run *= sf;                                                             \
        m_run = mnew;                                                            \
      }                                                                          \
      float ls0 = 0.f, ls1 = 0.f, ls2 = 0.f, ls3 = 0.f;                          \
      _Pragma("unroll")                                                          \
      for (int t = 0; t < 32; ++t) {                                             \
        float p = exp2f(pv_[t] - m_run);                                         \
        pv_[t] = p;                                                              \
        if ((t & 3) == 0) ls0 += p;                                              \
        else if ((t & 3) == 1) ls1 += p;                                         \
        else if ((t & 3) == 2) ls2 += p;                                         \
        else ls3 += p;                                                           \
      }                                                                          \
      float lsum = (ls0 + ls1) + (ls2 + ls3);                                    \
      lsum += __shfl_xor(lsum, 32);                                              \
      l_run += lsum;                                                             \
      _Pragma("unroll")                                                          \
      for (int c = 0; c < 4; ++c) {                                              \
        const int half_c = c >> 1;                                               \
        const int iA = half_c*16 + (((2*c)    ) & 3)*4;                          \
        const int iB = half_c*16 + (((2*c) + 1) & 3)*4;                          \
        unsigned wA0 = pk2(pv_[iA],   pv_[iA+1]);                                \
        unsigned wA1 = pk2(pv_[iA+2], pv_[iA+3]);                                \
        unsigned wB0 = pk2(pv_[iB],   pv_[iB+1]);                                \
        unsigned wB1 = pk2(pv_[iB+2], pv_[iB+3]);                                \
        unsigned ow0 = hi ? wB0 : wA0, ow1 = hi ? wB1 : wA1;                     \
        unsigned xw0 = hi ? wA0 : wB0, xw1 = hi ? wA1 : wB1;                     \
        unsigned yw0 = __shfl_xor(xw0, 32);                                      \
        unsigned yw1 = __shfl_xor(xw1, 32);                                      \
        u32x4 uu;                                                                \
        uu[0] = hi ? yw0 : ow0;                                                  \
        uu[1] = hi ? yw1 : ow1;                                                  \
        uu[2] = hi ? ow0 : yw0;                                                  \
        uu[3] = hi ? ow1 : yw1;                                                  \
        bf16x8 pa = __builtin_bit_cast(bf16x8, uu);                              \
        int sl = 2*c + hi;                                                       \
        int r0 = l5, r1 = 32 + l5;                                               \
        bf16x8 vf0 = *(const bf16x8*)&Vts[cb][r0*64 + ((sl ^ (r0 & 7)) << 3)];   \
        bf16x8 vf1 = *(const bf16x8*)&Vts[cb][r1*64 + ((sl ^ (r1 & 7)) << 3)];   \
        __builtin_amdgcn_s_setprio(1);                                           \
        o0 = __builtin_amdgcn_mfma_f32_32x32x16_bf16(pa, vf0, o0, 0, 0, 0);      \
        o1 = __builtin_amdgcn_mfma_f32_32x32x16_bf16(pa, vf1, o1, 0, 0, 0);      \
        __builtin_amdgcn_s_setprio(0);                                           \
      }                                                                          \
    }

  STAGE(0, 0);
  { int t1 = (ntile > 1) ? 1 : 0; STAGE(1, t1); }
  __syncthreads();                 // one-time full drain (tiles 0,1 landed)
  int cur = 0;
  for (int kt = 0; kt < ntile; ++kt) {
    asm volatile("s_waitcnt vmcnt(4)\n\ts_barrier" ::: "memory");
    int nb = cur + 2; if (nb >= 3) nb -= 3;
    int kts = kt + 2; if (kts > ntile - 1) kts = ntile - 1;
    STAGE(nb, kts);
    ATILE(cur, kt*64);
    ++cur; if (cur == 3) cur = 0;
  }
  asm volatile("s_waitcnt vmcnt(0)" ::: "memory");
  #undef STAGE
  #undef ATILE

  // epilogue
  float inv = 1.f / l_run;
  const int sbase = (b * SL) * DM + h * DK;
  #pragma unroll
  for (int reg = 0; reg < 16; ++reg) {
    int crow = (reg & 3) + ((reg >> 2) << 3) + (hi << 2);
    float iv = __shfl(inv, crow);
    int srow = q0 + w*32 + crow;
    CTXp[sbase + srow*DM + l5]      = (bf16)(o0[reg] * iv);
    CTXp[sbase + srow*DM + 32 + l5] = (bf16)(o1[reg] * iv);
  }
}

extern "C" void kernel_launch(void* const* d_in, const int* in_sizes, int n_in,
                              void* d_out, int out_size, void* d_ws, size_t ws_size,
                              hipStream_t stream) {
  const float* q  = (const float*)d_in[0];
  const float* k  = (const float*)d_in[1];
  const float* v  = (const float*)d_in[2];
  const int*  msk = (const int*)d_in[3];
  const float* Wq = (const float*)d_in[4];
  const float* bq = (const float*)d_in[5];
  const float* Wk = (const float*)d_in[6];
  const float* bk = (const float*)d_in[7];
  const float* Wv = (const float*)d_in[8];
  const float* bv = (const float*)d_in[9];
  const float* Wo = (const float*)d_in[10];
  const float* bo = (const float*)d_in[11];
  char* ws = (char*)d_ws;
  bf16* XQ  = (bf16*)(ws + 0);
  bf16* XK  = (bf16*)(ws + 8388608);
  bf16* XV  = (bf16*)(ws + 16777216);
  bf16* WTQ = (bf16*)(ws + 25165824);
  bf16* WTK = (bf16*)(ws + 27262976);
  bf16* WTV = (bf16*)(ws + 29360128);
  bf16* WTO = (bf16*)(ws + 31457280);
  bf16* QHb = (bf16*)(ws + 33554432);
  bf16* KHb = (bf16*)(ws + 41943040);
  bf16* VTb = (bf16*)(ws + 50331648);   // transposed [bh][d][s], compacted keys
  bf16* CTX = (bf16*)(ws + 58720256);   // total 64 MiB
  float* out = (float*)d_out;
  // scratch stashed in d_out (fully overwritten by out_gemm at the end):
  int* gidx = (int*)d_out;                       // 2*2048 ints = 16 KB
  int* nvp  = (int*)((char*)d_out + 16384);      // 2 ints

  mask_scan_kernel<<<dim3(2), 256, 0, stream>>>(msk, gidx, nvp);
  prep_kernel<<<dim3(7168), 256, 0, stream>>>(q, k, v, Wq, Wk, Wv, Wo,
                                              XQ, XK, XV, WTQ, WTK, WTV, WTO,
                                              gidx, nvp);
  proj_gemm_kernel<<<dim3(512, 3), 256, 0, stream>>>(XQ, XK, XV, WTQ, WTK, WTV,
                                                     bq, bk, bv, QHb, KHb, VTb);
  attn_kernel<<<dim3(512), 256, 0, stream>>>(QHb, KHb, VTb, nvp, CTX);
  out_gemm_kernel<<<dim3(512), 256, 0, stream>>>(CTX, WTO, bo, out);
}